// Round 1
// baseline (628.271 us; speedup 1.0000x reference)
//
#include <hip/hip_runtime.h>
#include <math.h>

#define BB 2
#define TT 128
#define NN 64
#define DD 128
#define HH 8
#define DKK 16
#define DEE 32
#define LWW 8
#define BNN (BB*NN)   // 128

// ---------------- Kernel 1: QKV GEMM (16384x128 @ 128x384) ----------------
// Grid 512 blocks x 256 threads; each block does 32 rows.
// Outputs: Q[bn][t][h*16+dk], K[bn][h][s][dk], V[bn][h][dk][s]
__global__ __launch_bounds__(256) void qkv_kernel(
    const float* __restrict__ node, const float* __restrict__ Wqkv,
    const float* __restrict__ bqkv,
    float* __restrict__ Q, float* __restrict__ K, float* __restrict__ V) {
  __shared__ float xs[32 * 128];     // 16 KB
  __shared__ float wl[32 * 384];     // 48 KB
  const int tid = threadIdx.x;
  const int row0 = blockIdx.x * 32;

  // load x tile: x[bn,t,d] = node[b,t,n,d]
  {
    int i4 = tid;  // 1024 float4 loads, 4 iters
    for (; i4 < 1024; i4 += 256) {
      int r = i4 >> 5, d4 = i4 & 31;
      int rowg = row0 + r;
      int bn = rowg >> 7, t = rowg & 127;
      int b = bn >> 6, n = bn & 63;
      float4 v = *(const float4*)&node[(((size_t)(b * TT + t)) * NN + n) * DD + d4 * 4];
      *(float4*)&xs[r * 128 + d4 * 4] = v;
    }
  }

  float acc[48];
#pragma unroll
  for (int i = 0; i < 48; ++i) acc[i] = 0.f;
  const int tr = tid >> 5;   // 0..7  -> rows tr*4 .. tr*4+3
  const int tc = tid & 31;   // 0..31 -> cols tc*12 .. tc*12+11

  for (int ct = 0; ct < 4; ++ct) {
    __syncthreads();
    for (int i4 = tid; i4 < 3072; i4 += 256) {  // 32x384 floats = 3072 float4
      int c = i4 / 96, j4 = i4 % 96;
      *(float4*)&wl[c * 384 + j4 * 4] =
          *(const float4*)&Wqkv[(size_t)(ct * 32 + c) * 384 + j4 * 4];
    }
    __syncthreads();
#pragma unroll 4
    for (int cl = 0; cl < 32; ++cl) {
      float xr[4];
#pragma unroll
      for (int i = 0; i < 4; ++i) xr[i] = xs[(tr * 4 + i) * 128 + ct * 32 + cl];
      float4 w0 = *(const float4*)&wl[cl * 384 + tc * 12 + 0];
      float4 w1 = *(const float4*)&wl[cl * 384 + tc * 12 + 4];
      float4 w2 = *(const float4*)&wl[cl * 384 + tc * 12 + 8];
#pragma unroll
      for (int i = 0; i < 4; ++i) {
        acc[i * 12 + 0] += xr[i] * w0.x;  acc[i * 12 + 1] += xr[i] * w0.y;
        acc[i * 12 + 2] += xr[i] * w0.z;  acc[i * 12 + 3] += xr[i] * w0.w;
        acc[i * 12 + 4] += xr[i] * w1.x;  acc[i * 12 + 5] += xr[i] * w1.y;
        acc[i * 12 + 6] += xr[i] * w1.z;  acc[i * 12 + 7] += xr[i] * w1.w;
        acc[i * 12 + 8] += xr[i] * w2.x;  acc[i * 12 + 9] += xr[i] * w2.y;
        acc[i * 12 +10] += xr[i] * w2.z;  acc[i * 12 +11] += xr[i] * w2.w;
      }
    }
  }

  // epilogue: cols tc*12..+11 lie within one h block (48 cols); j = h*48+dk*3+c
  const int h = tc >> 2;
  const int dk0 = (tc & 3) * 4;
#pragma unroll
  for (int i = 0; i < 4; ++i) {
    int rowg = row0 + tr * 4 + i;
    int bn = rowg >> 7, t = rowg & 127;
    float qv[4], kv[4], vv[4];
#pragma unroll
    for (int dl = 0; dl < 4; ++dl) {
      int jb = h * 48 + (dk0 + dl) * 3;
      qv[dl] = acc[i * 12 + dl * 3 + 0] + bqkv[jb + 0];
      kv[dl] = acc[i * 12 + dl * 3 + 1] + bqkv[jb + 1];
      vv[dl] = acc[i * 12 + dl * 3 + 2] + bqkv[jb + 2];
    }
    *(float4*)&Q[(size_t)rowg * 128 + h * 16 + dk0] = *(float4*)qv;
    *(float4*)&K[(((size_t)(bn * 8 + h)) * 128 + t) * 16 + dk0] = *(float4*)kv;
#pragma unroll
    for (int dl = 0; dl < 4; ++dl)
      V[(((size_t)(bn * 8 + h)) * 16 + dk0 + dl) * 128 + t] = vv[dl];
  }
}

// ---------------- Kernel 2: fused attention + edge update ----------------
// One block = (bn, 8 consecutive t rows). 2048 blocks x 256 threads.
__global__ __launch_bounds__(256) void attn_kernel(
    const float* __restrict__ Q, const float* __restrict__ K,
    const float* __restrict__ V, const float* __restrict__ tv,
    const int* __restrict__ mask,
    const float* __restrict__ Wg, const float* __restrict__ bg,
    const float* __restrict__ Wout, const float* __restrict__ bout,
    const float* __restrict__ Wupd, const float* __restrict__ bupd,
    float* __restrict__ out0, float* __restrict__ out1) {
  __shared__ float sc[8 * 8 * 128];  // [tt][h][s] 32 KB
  __shared__ float qs[8 * 128];      // q rows; later reused as xo_pre
  __shared__ float swg[DEE * HH];    // W_g [c][h]
  __shared__ float swu[HH * DEE];    // W_upd [h][e]
  __shared__ float sbg[HH];
  __shared__ float sbu[DEE];
  __shared__ int smask[TT];

  const int tid = threadIdx.x;
  // XCD-locality swizzle: same bn -> same (blockIdx%8) class
  const int xcd = blockIdx.x & 7;
  const int i = blockIdx.x >> 3;          // 0..255
  const int bn = xcd * 16 + (i & 15);     // 0..127
  const int t0 = (i >> 4) * 8;            // 0..120
  const int b = bn >> 6, n = bn & 63;

  swg[tid & 255] = Wg[tid & 255];
  swu[tid & 255] = Wupd[tid & 255];
  if (tid < DEE) sbu[tid] = bupd[tid];
  if (tid < HH) sbg[tid] = bg[tid];
  if (tid < TT) smask[tid] = mask[b * TT + tid];
  {  // load 8 q rows (1024 floats = 256 float4: one per thread)
    int tt = tid >> 5, d4 = tid & 31;
    *(float4*)&qs[tt * 128 + d4 * 4] =
        *(const float4*)&Q[((size_t)(bn * TT + t0 + tt)) * 128 + d4 * 4];
  }
  __syncthreads();

  // ---- scores = q.k / 4 ----
  for (int idx = tid; idx < HH * TT; idx += 256) {
    int h = idx >> 7, s = idx & 127;
    const float4* kp = (const float4*)&K[(((size_t)(bn * 8 + h)) * 128 + s) * 16];
    float4 k0 = kp[0], k1 = kp[1], k2 = kp[2], k3 = kp[3];
#pragma unroll
    for (int t8 = 0; t8 < 8; ++t8) {
      const float4* qp = (const float4*)&qs[t8 * 128 + h * 16];
      float4 q0 = qp[0], q1 = qp[1], q2 = qp[2], q3 = qp[3];
      float d = q0.x * k0.x + q0.y * k0.y + q0.z * k0.z + q0.w * k0.w +
                q1.x * k1.x + q1.y * k1.y + q1.z * k1.z + q1.w * k1.w +
                q2.x * k2.x + q2.y * k2.y + q2.z * k2.z + q2.w * k2.w +
                q3.x * k3.x + q3.y * k3.y + q3.z * k3.z + q3.w * k3.w;
      sc[(t8 * 8 + h) * 128 + s] = d * 0.25f;
    }
  }
  __syncthreads();

  // ---- banded edge bias: g = tv @ Wg + bg, only |t-s|<=LW ----
  if (tid < 8 * (2 * LWW + 1)) {
    int t8 = tid / 17, ds = tid % 17;
    int t = t0 + t8, s = t - LWW + ds;
    if (s >= 0 && s < TT) {
      const float4* tp = (const float4*)&tv[(((size_t)(bn * TT + t)) * TT + s) * DEE];
      float gh[HH];
#pragma unroll
      for (int h = 0; h < HH; ++h) gh[h] = sbg[h];
#pragma unroll
      for (int c4 = 0; c4 < 8; ++c4) {
        float4 tvv = tp[c4];
#pragma unroll
        for (int h = 0; h < HH; ++h) {
          gh[h] += tvv.x * swg[(c4 * 4 + 0) * 8 + h] +
                   tvv.y * swg[(c4 * 4 + 1) * 8 + h] +
                   tvv.z * swg[(c4 * 4 + 2) * 8 + h] +
                   tvv.w * swg[(c4 * 4 + 3) * 8 + h];
        }
      }
#pragma unroll
      for (int h = 0; h < HH; ++h) sc[(t8 * 8 + h) * 128 + s] += gh[h];
    }
  }
  __syncthreads();

  // ---- clip + key-mask replace ----
  for (int idx = tid; idx < 8192; idx += 256) {
    int s = idx & 127;
    float v = sc[idx];
    v = fminf(fmaxf(v, -5.f), 5.f);
    if (smask[s] == 0) v = 1e-28f;
    sc[idx] = v;
  }
  __syncthreads();

  // ---- tv_out = sc @ W_upd + b_upd (full T x T band-free GEMV, coalesced) ----
  for (int t8 = 0; t8 < 8; ++t8) {
    int t = t0 + t8;
    float* op = out1 + (((size_t)(bn * TT + t)) * TT) * DEE;
    for (int i4 = tid; i4 < TT * DEE / 4; i4 += 256) {  // 1024 float4
      int s = i4 >> 3, e4 = i4 & 7;
      float4 o = *(const float4*)&sbu[e4 * 4];
#pragma unroll
      for (int h = 0; h < HH; ++h) {
        float f = sc[(t8 * 8 + h) * 128 + s];
        float4 w = *(const float4*)&swu[h * 32 + e4 * 4];
        o.x += f * w.x; o.y += f * w.y; o.z += f * w.z; o.w += f * w.w;
      }
      *(float4*)&op[s * DEE + e4 * 4] = o;
    }
  }
  __syncthreads();

  // ---- softmax in place over s (4 lanes per row) ----
  {
    int row = tid >> 2;  // 0..63 : tt=row>>3, h=row&7
    int l4 = tid & 3;
    float* r = &sc[row * 128];
    float m = -1e30f;
#pragma unroll 8
    for (int k = 0; k < 32; ++k) m = fmaxf(m, r[l4 * 32 + k]);
    m = fmaxf(m, __shfl_xor(m, 1));
    m = fmaxf(m, __shfl_xor(m, 2));
    float ssum = 0.f;
#pragma unroll 8
    for (int k = 0; k < 32; ++k) {
      float e = __expf(r[l4 * 32 + k] - m);
      r[l4 * 32 + k] = e;
      ssum += e;
    }
    ssum += __shfl_xor(ssum, 1);
    ssum += __shfl_xor(ssum, 2);
    float inv = 1.f / ssum;
#pragma unroll 8
    for (int k = 0; k < 32; ++k) {
      int s = l4 * 32 + k;
      r[s] = (smask[s] == 0) ? 0.f : r[s] * inv;
    }
  }
  __syncthreads();

  // ---- xo_pre = attn @ V  (into qs) ----
  for (int u = 0; u < 4; ++u) {
    int idx = tid + u * 256;
    int t8 = idx >> 7, hd = idx & 127;
    int h = hd >> 4, dk = hd & 15;
    const float4* vp = (const float4*)&V[(((size_t)(bn * 8 + h)) * 16 + dk) * 128];
    const float4* ap = (const float4*)&sc[(t8 * 8 + h) * 128];
    float a = 0.f;
#pragma unroll 8
    for (int s4 = 0; s4 < 32; ++s4) {
      float4 vv = vp[s4], av = ap[s4];
      a += av.x * vv.x + av.y * vv.y + av.z * vv.z + av.w * vv.w;
    }
    qs[t8 * 128 + hd] = a;
  }
  __syncthreads();

  // ---- out proj: out0[b,t,n,:] = xo_pre @ W_out + b_out ----
  {
    int d = tid & 127, tg = tid >> 7;
    float accp[4];
#pragma unroll
    for (int u = 0; u < 4; ++u) accp[u] = bout[d];
    for (int c = 0; c < 128; ++c) {
      float w = Wout[c * 128 + d];
#pragma unroll
      for (int u = 0; u < 4; ++u) accp[u] += qs[(tg * 4 + u) * 128 + c] * w;
    }
#pragma unroll
    for (int u = 0; u < 4; ++u) {
      int t = t0 + tg * 4 + u;
      out0[(((size_t)(b * TT + t)) * NN + n) * DD + d] = accp[u];
    }
  }
}

extern "C" void kernel_launch(void* const* d_in, const int* in_sizes, int n_in,
                              void* d_out, int out_size, void* d_ws, size_t ws_size,
                              hipStream_t stream) {
  const float* node = (const float*)d_in[0];
  const float* tv   = (const float*)d_in[1];
  const int*   mask = (const int*)d_in[2];
  // d_in[3] local_mask: banded |i-j|<=LW, synthesized in-kernel
  const float* Wqkv = (const float*)d_in[4];
  const float* bqkv = (const float*)d_in[5];
  const float* Wg   = (const float*)d_in[6];
  const float* bg   = (const float*)d_in[7];
  const float* Wout = (const float*)d_in[8];
  const float* bout = (const float*)d_in[9];
  const float* Wupd = (const float*)d_in[10];
  const float* bupd = (const float*)d_in[11];

  float* out0 = (float*)d_out;                       // (B,T,N,D)
  float* out1 = out0 + (size_t)BB * TT * NN * DD;    // (B,N,T,T,DE)

  float* Q = (float*)d_ws;                           // BN*T*128 each
  float* K = Q + (size_t)BNN * TT * DD;
  float* V = K + (size_t)BNN * TT * DD;

  qkv_kernel<<<512, 256, 0, stream>>>(node, Wqkv, bqkv, Q, K, V);
  attn_kernel<<<2048, 256, 0, stream>>>(Q, K, V, tv, mask, Wg, bg, Wout, bout,
                                        Wupd, bupd, out0, out1);
}

// Round 3
// 576.896 us; speedup vs baseline: 1.0891x; 1.0891x over previous
//
#include <hip/hip_runtime.h>
#include <math.h>

#define BB 2
#define TT 128
#define NN 64
#define DD 128
#define HH 8
#define DKK 16
#define DEE 32
#define LWW 8
#define BNN (BB*NN)   // 128

typedef float floatx4 __attribute__((ext_vector_type(4)));

// ---------------- Kernel 1: QKV GEMM (16384x128 @ 128x384) ----------------
// Grid 512 blocks x 256 threads; each block does 32 rows. BK=16 -> 40KB LDS,
// 4 blocks/CU.
// Outputs: Q[bn][t][h*16+dk], K[bn][h][s][dk], V[bn][h][dk][s]
__global__ __launch_bounds__(256) void qkv_kernel(
    const float* __restrict__ node, const float* __restrict__ Wqkv,
    const float* __restrict__ bqkv,
    float* __restrict__ Q, float* __restrict__ K, float* __restrict__ V) {
  __shared__ float xs[32 * 128];     // 16 KB
  __shared__ float wl[16 * 384];     // 24 KB
  const int tid = threadIdx.x;
  const int row0 = blockIdx.x * 32;

  // load x tile: x[bn,t,d] = node[b,t,n,d]
  for (int i4 = tid; i4 < 1024; i4 += 256) {
    int r = i4 >> 5, d4 = i4 & 31;
    int rowg = row0 + r;
    int bn = rowg >> 7, t = rowg & 127;
    int b = bn >> 6, n = bn & 63;
    float4 v = *(const float4*)&node[(((size_t)(b * TT + t)) * NN + n) * DD + d4 * 4];
    *(float4*)&xs[r * 128 + d4 * 4] = v;
  }

  float acc[48];
#pragma unroll
  for (int i = 0; i < 48; ++i) acc[i] = 0.f;
  const int tr = tid >> 5;   // 0..7  -> rows tr*4 .. tr*4+3
  const int tc = tid & 31;   // 0..31 -> cols tc*12 .. tc*12+11

  for (int ct = 0; ct < 8; ++ct) {
    __syncthreads();
    for (int i4 = tid; i4 < 1536; i4 += 256) {  // 16x384 floats = 1536 float4
      int c = i4 / 96, j4 = i4 % 96;
      *(float4*)&wl[c * 384 + j4 * 4] =
          *(const float4*)&Wqkv[(size_t)(ct * 16 + c) * 384 + j4 * 4];
    }
    __syncthreads();
#pragma unroll 4
    for (int cl = 0; cl < 16; ++cl) {
      float xr[4];
#pragma unroll
      for (int i = 0; i < 4; ++i) xr[i] = xs[(tr * 4 + i) * 128 + ct * 16 + cl];
      float4 w0 = *(const float4*)&wl[cl * 384 + tc * 12 + 0];
      float4 w1 = *(const float4*)&wl[cl * 384 + tc * 12 + 4];
      float4 w2 = *(const float4*)&wl[cl * 384 + tc * 12 + 8];
#pragma unroll
      for (int i = 0; i < 4; ++i) {
        acc[i * 12 + 0] += xr[i] * w0.x;  acc[i * 12 + 1] += xr[i] * w0.y;
        acc[i * 12 + 2] += xr[i] * w0.z;  acc[i * 12 + 3] += xr[i] * w0.w;
        acc[i * 12 + 4] += xr[i] * w1.x;  acc[i * 12 + 5] += xr[i] * w1.y;
        acc[i * 12 + 6] += xr[i] * w1.z;  acc[i * 12 + 7] += xr[i] * w1.w;
        acc[i * 12 + 8] += xr[i] * w2.x;  acc[i * 12 + 9] += xr[i] * w2.y;
        acc[i * 12 +10] += xr[i] * w2.z;  acc[i * 12 +11] += xr[i] * w2.w;
      }
    }
  }

  // epilogue: cols tc*12..+11 lie within one h block (48 cols); j = h*48+dk*3+c
  const int h = tc >> 2;
  const int dk0 = (tc & 3) * 4;
#pragma unroll
  for (int i = 0; i < 4; ++i) {
    int rowg = row0 + tr * 4 + i;
    int bn = rowg >> 7, t = rowg & 127;
    float qv[4], kv[4], vv[4];
#pragma unroll
    for (int dl = 0; dl < 4; ++dl) {
      int jb = h * 48 + (dk0 + dl) * 3;
      qv[dl] = acc[i * 12 + dl * 3 + 0] + bqkv[jb + 0];
      kv[dl] = acc[i * 12 + dl * 3 + 1] + bqkv[jb + 1];
      vv[dl] = acc[i * 12 + dl * 3 + 2] + bqkv[jb + 2];
    }
    *(float4*)&Q[(size_t)rowg * 128 + h * 16 + dk0] = *(float4*)qv;
    *(float4*)&K[(((size_t)(bn * 8 + h)) * 128 + t) * 16 + dk0] = *(float4*)kv;
#pragma unroll
    for (int dl = 0; dl < 4; ++dl)
      V[(((size_t)(bn * 8 + h)) * 16 + dk0 + dl) * 128 + t] = vv[dl];
  }
}

// ---------------- Kernel 2: fused attention + edge update ----------------
// One block = (bn, 8 consecutive t rows). 2048 blocks x 256 threads.
__global__ __launch_bounds__(256) void attn_kernel(
    const float* __restrict__ Q, const float* __restrict__ K,
    const float* __restrict__ V, const float* __restrict__ tv,
    const int* __restrict__ mask,
    const float* __restrict__ Wg, const float* __restrict__ bg,
    const float* __restrict__ Wout, const float* __restrict__ bout,
    const float* __restrict__ Wupd, const float* __restrict__ bupd,
    float* __restrict__ out0, float* __restrict__ out1) {
  __shared__ float sc[8 * 8 * 128];  // [tt][h][s] 32 KB
  __shared__ float qs[8 * 128];      // q rows; later reused as xo_pre
  __shared__ float swg[DEE * HH];    // W_g [c][h]
  __shared__ float swu[HH * DEE];    // W_upd [h][e]
  __shared__ float sbg[HH];
  __shared__ float sbu[DEE];
  __shared__ int smask[TT];

  const int tid = threadIdx.x;
  // XCD-locality swizzle: same bn -> same (blockIdx%8) class
  const int xcd = blockIdx.x & 7;
  const int i = blockIdx.x >> 3;          // 0..255
  const int bn = xcd * 16 + (i & 15);     // 0..127
  const int t0 = (i >> 4) * 8;            // 0..120
  const int b = bn >> 6, n = bn & 63;

  swg[tid & 255] = Wg[tid & 255];
  swu[tid & 255] = Wupd[tid & 255];
  if (tid < DEE) sbu[tid] = bupd[tid];
  if (tid < HH) sbg[tid] = bg[tid];
  if (tid < TT) smask[tid] = mask[b * TT + tid];
  {  // load 8 q rows (1024 floats = 256 float4: one per thread)
    int tt = tid >> 5, d4 = tid & 31;
    *(float4*)&qs[tt * 128 + d4 * 4] =
        *(const float4*)&Q[((size_t)(bn * TT + t0 + tt)) * 128 + d4 * 4];
  }
  __syncthreads();

  // ---- scores = q.k / 4 ; clip+mask applied here for OUT-OF-BAND entries,
  //      raw value left in-band (g phase finishes those) ----
  for (int idx = tid; idx < HH * TT; idx += 256) {
    int h = idx >> 7, s = idx & 127;
    const float4* kp = (const float4*)&K[(((size_t)(bn * 8 + h)) * 128 + s) * 16];
    float4 k0 = kp[0], k1 = kp[1], k2 = kp[2], k3 = kp[3];
    int m0 = smask[s];
#pragma unroll
    for (int t8 = 0; t8 < 8; ++t8) {
      const float4* qp = (const float4*)&qs[t8 * 128 + h * 16];
      float4 q0 = qp[0], q1 = qp[1], q2 = qp[2], q3 = qp[3];
      float d = q0.x * k0.x + q0.y * k0.y + q0.z * k0.z + q0.w * k0.w +
                q1.x * k1.x + q1.y * k1.y + q1.z * k1.z + q1.w * k1.w +
                q2.x * k2.x + q2.y * k2.y + q2.z * k2.z + q2.w * k2.w +
                q3.x * k3.x + q3.y * k3.y + q3.z * k3.z + q3.w * k3.w;
      float v = d * 0.25f;
      int t = t0 + t8;
      bool inband = (s >= t - LWW) && (s <= t + LWW);
      if (!inband) {
        v = fminf(fmaxf(v, -5.f), 5.f);
        if (m0 == 0) v = 1e-28f;
      }
      sc[(t8 * 8 + h) * 128 + s] = v;
    }
  }
  __syncthreads();

  // ---- banded edge bias: g = tv @ Wg + bg, then clip+mask (band only) ----
  if (tid < 8 * (2 * LWW + 1)) {
    int t8 = tid / 17, ds = tid % 17;
    int t = t0 + t8, s = t - LWW + ds;
    if (s >= 0 && s < TT) {
      const float4* tp = (const float4*)&tv[(((size_t)(bn * TT + t)) * TT + s) * DEE];
      float gh[HH];
#pragma unroll
      for (int h = 0; h < HH; ++h) gh[h] = sbg[h];
#pragma unroll
      for (int c4 = 0; c4 < 8; ++c4) {
        float4 tvv = tp[c4];
#pragma unroll
        for (int h = 0; h < HH; ++h) {
          gh[h] += tvv.x * swg[(c4 * 4 + 0) * 8 + h] +
                   tvv.y * swg[(c4 * 4 + 1) * 8 + h] +
                   tvv.z * swg[(c4 * 4 + 2) * 8 + h] +
                   tvv.w * swg[(c4 * 4 + 3) * 8 + h];
        }
      }
      int m0 = smask[s];
#pragma unroll
      for (int h = 0; h < HH; ++h) {
        float v = sc[(t8 * 8 + h) * 128 + s] + gh[h];
        v = fminf(fmaxf(v, -5.f), 5.f);
        if (m0 == 0) v = 1e-28f;
        sc[(t8 * 8 + h) * 128 + s] = v;
      }
    }
  }
  __syncthreads();

  // ---- tv_out = sc @ W_upd + b_upd; W_upd column hoisted to registers;
  //      nontemporal float4 stores (256 MB never re-read) ----
  {
    const int e4 = tid & 7;   // output float4 within DE
    const int s0 = tid >> 3;  // 0..31
    float4 w[HH];
#pragma unroll
    for (int h = 0; h < HH; ++h) w[h] = *(const float4*)&swu[h * 32 + e4 * 4];
    float4 bu = *(const float4*)&sbu[e4 * 4];
    for (int t8 = 0; t8 < 8; ++t8) {
      float* op = out1 + (((size_t)(bn * TT + t0 + t8)) * TT) * DEE;
#pragma unroll
      for (int si = 0; si < 4; ++si) {
        int s = s0 + si * 32;
        float4 o = bu;
#pragma unroll
        for (int h = 0; h < HH; ++h) {
          float f = sc[(t8 * 8 + h) * 128 + s];
          o.x += f * w[h].x; o.y += f * w[h].y;
          o.z += f * w[h].z; o.w += f * w[h].w;
        }
        floatx4 ov; ov.x = o.x; ov.y = o.y; ov.z = o.z; ov.w = o.w;
        __builtin_nontemporal_store(ov, (floatx4*)&op[s * DEE + e4 * 4]);
      }
    }
  }
  __syncthreads();

  // ---- softmax in place over s: 32 lanes per row, bank-conflict-free ----
  {
    const int l = tid & 31;      // lane within row-group -> bank l
    const int rsub = tid >> 5;   // 0..7
#pragma unroll
    for (int p = 0; p < 8; ++p) {
      int row = p * 8 + rsub;
      float* r = &sc[row * 128];
      float x0 = r[l], x1 = r[l + 32], x2 = r[l + 64], x3 = r[l + 96];
      float m = fmaxf(fmaxf(x0, x1), fmaxf(x2, x3));
      m = fmaxf(m, __shfl_xor(m, 1));
      m = fmaxf(m, __shfl_xor(m, 2));
      m = fmaxf(m, __shfl_xor(m, 4));
      m = fmaxf(m, __shfl_xor(m, 8));
      m = fmaxf(m, __shfl_xor(m, 16));
      float e0 = __expf(x0 - m), e1 = __expf(x1 - m),
            e2 = __expf(x2 - m), e3 = __expf(x3 - m);
      float ssum = e0 + e1 + e2 + e3;
      ssum += __shfl_xor(ssum, 1);
      ssum += __shfl_xor(ssum, 2);
      ssum += __shfl_xor(ssum, 4);
      ssum += __shfl_xor(ssum, 8);
      ssum += __shfl_xor(ssum, 16);
      float inv = 1.f / ssum;
      r[l]      = (smask[l]      == 0) ? 0.f : e0 * inv;
      r[l + 32] = (smask[l + 32] == 0) ? 0.f : e1 * inv;
      r[l + 64] = (smask[l + 64] == 0) ? 0.f : e2 * inv;
      r[l + 96] = (smask[l + 96] == 0) ? 0.f : e3 * inv;
    }
  }
  __syncthreads();

  // ---- xo_pre = attn @ V  (into qs) ----
  for (int u = 0; u < 4; ++u) {
    int idx = tid + u * 256;
    int t8 = idx >> 7, hd = idx & 127;
    int h = hd >> 4, dk = hd & 15;
    const float4* vp = (const float4*)&V[(((size_t)(bn * 8 + h)) * 16 + dk) * 128];
    const float4* ap = (const float4*)&sc[(t8 * 8 + h) * 128];
    float a = 0.f;
#pragma unroll 8
    for (int s4 = 0; s4 < 32; ++s4) {
      float4 vv = vp[s4], av = ap[s4];
      a += av.x * vv.x + av.y * vv.y + av.z * vv.z + av.w * vv.w;
    }
    qs[t8 * 128 + hd] = a;
  }
  __syncthreads();

  // ---- out proj: out0[b,t,n,:] = xo_pre @ W_out + b_out ----
  {
    int d = tid & 127, tg = tid >> 7;
    float accp[4];
#pragma unroll
    for (int u = 0; u < 4; ++u) accp[u] = bout[d];
    for (int c = 0; c < 128; ++c) {
      float w = Wout[c * 128 + d];
#pragma unroll
      for (int u = 0; u < 4; ++u) accp[u] += qs[(tg * 4 + u) * 128 + c] * w;
    }
#pragma unroll
    for (int u = 0; u < 4; ++u) {
      int t = t0 + tg * 4 + u;
      __builtin_nontemporal_store(accp[u],
          &out0[(((size_t)(b * TT + t)) * NN + n) * DD + d]);
    }
  }
}

extern "C" void kernel_launch(void* const* d_in, const int* in_sizes, int n_in,
                              void* d_out, int out_size, void* d_ws, size_t ws_size,
                              hipStream_t stream) {
  const float* node = (const float*)d_in[0];
  const float* tv   = (const float*)d_in[1];
  const int*   mask = (const int*)d_in[2];
  // d_in[3] local_mask: banded |i-j|<=LW, synthesized in-kernel
  const float* Wqkv = (const float*)d_in[4];
  const float* bqkv = (const float*)d_in[5];
  const float* Wg   = (const float*)d_in[6];
  const float* bg   = (const float*)d_in[7];
  const float* Wout = (const float*)d_in[8];
  const float* bout = (const float*)d_in[9];
  const float* Wupd = (const float*)d_in[10];
  const float* bupd = (const float*)d_in[11];

  float* out0 = (float*)d_out;                       // (B,T,N,D)
  float* out1 = out0 + (size_t)BB * TT * NN * DD;    // (B,N,T,T,DE)

  float* Q = (float*)d_ws;                           // BN*T*128 each
  float* K = Q + (size_t)BNN * TT * DD;
  float* V = K + (size_t)BNN * TT * DD;

  qkv_kernel<<<512, 256, 0, stream>>>(node, Wqkv, bqkv, Q, K, V);
  attn_kernel<<<2048, 256, 0, stream>>>(Q, K, V, tv, mask, Wg, bg, Wout, bout,
                                        Wupd, bupd, out0, out1);
}